// Round 2
// baseline (1197.474 us; speedup 1.0000x reference)
//
#include <hip/hip_runtime.h>
#include <stdint.h>

typedef __attribute__((ext_vector_type(8))) _Float16 h8v;
typedef __attribute__((ext_vector_type(4))) float f4v;

#define NLVL 6
#define TSZ (1u << 19)

__device__ __forceinline__ float b2f(unsigned short u){
  union { unsigned int i; float f; } v; v.i = ((unsigned)u) << 16; return v.f;
}
__device__ __forceinline__ unsigned short f2b(float f){
  unsigned x = __float_as_uint(f);
  x = (x + 0x7fffu + ((x >> 16) & 1u)) >> 16;
  return (unsigned short)x;
}
__device__ __forceinline__ unsigned short f2h(float f){
  union { _Float16 h; unsigned short u; } v; v.h = (_Float16)f; return v.u;
}
// flag==1: buffers are bf16; flag==0: buffers are f32
__device__ __forceinline__ float ldx(const void* p, long i, int isb){
  return isb ? b2f(((const unsigned short*)p)[i]) : ((const float*)p)[i];
}

// ---------------- dtype sniffing ----------------
__global__ void kdetect(const unsigned short* inpos, int* flag){
  __shared__ int cnt;
  if (threadIdx.x == 0) cnt = 0;
  __syncthreads();
  float f = b2f(inpos[threadIdx.x * 2]);
  int ok = (f == f) && (fabsf(f) <= 1.0f);
  atomicAdd(&cnt, ok);
  __syncthreads();
  if (threadIdx.x == 0) *flag = (cnt >= 120);
}

// ---------------- ws layout ----------------
// [0,16):            int flag
// [16, +L*N*2*4):    grid features g[level][point][2] (f32)
// [wt_off, +12*65536*2): transposed weights Wt[wi][n][k] fp16, wi=0..5 Ws, 6..11 Wh
// [c_off, +7168*4):  f32 consts: W0s[768] | sb0[256] | sbs[1536] | sbh[1536] | A2pi[3072]

__global__ void kconsts(const void* ffnA, const void* W0, const void* b0,
                        const void* bs, const void* bh, char* ws, int Npts){
  const int flag = *(const int*)ws;
  const size_t wt_off = 16 + (size_t)NLVL * Npts * 8;
  float* cst = (float*)(ws + wt_off + (size_t)12 * 65536 * 2);
  int idx = blockIdx.x * 256 + threadIdx.x;
  float v;
  if (idx < 768)        v = 5.0f  * ldx(W0, idx, flag);          // 5*W0  (w0_sin folded)
  else if (idx < 1024)  v = 5.0f  * ldx(b0, idx - 768, flag);    // 5*b0
  else if (idx < 2560)  v = 5.0f  * ldx(bs, idx - 1024, flag);   // 5*bs
  else if (idx < 4096)  v = 10.0f * ldx(bh, idx - 2560, flag);   // 10*bh
  else { int j = idx - 4096; int l = j >> 9;                     // 2*pi*sigma_l*ffn_A
         v = 31.415926535897932f * (float)(1 << l) * ldx(ffnA, j, flag); }
  cst[idx] = v;
}

// ---------------- weight transpose: Wt[wi][n][k] = W[wi][k][n], fp16 ----------------
// bf16 source values (|w|<=0.031, 7 mantissa bits) convert to fp16 exactly.
__global__ void kwt(const void* Wsv, const void* Whv, char* ws, int Npts){
  const int flag = *(const int*)ws;
  unsigned short* wt = (unsigned short*)(ws + 16 + (size_t)NLVL * Npts * 8);
  int e = blockIdx.x * 256 + threadIdx.x;          // 786432 total
  int wi = e >> 16, r = e & 65535, n = r >> 8, k = r & 255;
  const void* src = (wi < 6) ? Wsv : Whv;
  int m = (wi < 6) ? wi : wi - 6;
  long si = (long)m * 65536 + k * 256 + n;
  float w = flag ? b2f(((const unsigned short*)src)[si]) : ((const float*)src)[si];
  wt[e] = f2h(w);
}

// ---------------- hash grid features ----------------
__global__ void kgrid(const void* inpos, const void* tbl, char* ws, int Npts){
  const int flag = *(const int*)ws;
  float* gf = (float*)(ws + 16);
  int n = blockIdx.x * 256 + threadIdx.x;
  int l = blockIdx.y;
  long b3 = (long)n * 3;
  float x = ldx(inpos, b3 + 0, flag), y = ldx(inpos, b3 + 1, flag), z = ldx(inpos, b3 + 2, flag);
  float res = (float)(16 << l);
  float px = ((x + 1.0f) * 0.5f) * res;   // exact pow2 scales -> floor matches ref
  float py = ((y + 1.0f) * 0.5f) * res;
  float pz = ((z + 1.0f) * 0.5f) * res;
  float fx = floorf(px), fy = floorf(py), fz = floorf(pz);
  float rx = px - fx, ry = py - fy, rz = pz - fz;
  unsigned cx = (unsigned)(int)fx, cy = (unsigned)(int)fy, cz = (unsigned)(int)fz;
  unsigned ax0 = cx,                 ax1 = cx + 1u;
  unsigned ay0 = cy * 2654435761u,   ay1 = (cy + 1u) * 2654435761u;
  unsigned az0 = cz * 805459861u,    az1 = (cz + 1u) * 805459861u;
  float g0 = 0.f, g1 = 0.f;
  #pragma unroll
  for (int c = 0; c < 8; c++){
    unsigned h = (((c & 4) ? ax1 : ax0) ^ ((c & 2) ? ay1 : ay0) ^ ((c & 1) ? az1 : az0)) & (TSZ - 1u);
    float w = ((c & 4) ? rx : 1.0f - rx) * ((c & 2) ? ry : 1.0f - ry) * ((c & 1) ? rz : 1.0f - rz);
    long e = ((long)l * TSZ + h) * 2;
    float f0, f1;
    if (flag){
      unsigned v = *(const unsigned*)((const unsigned short*)tbl + e);
      f0 = b2f((unsigned short)(v & 0xffffu)); f1 = b2f((unsigned short)(v >> 16));
    } else {
      const float* tp = (const float*)tbl + e; f0 = tp[0]; f1 = tp[1];
    }
    g0 += w * f0; g1 += w * f1;
  }
  float2 o; o.x = g0; o.y = g1;
  *(float2*)(gf + ((long)l * Npts + n) * 2) = o;
}

// ---------------- fused MLP ----------------
// 512 threads = 8 waves; block tile 128 rows x 256 cols; wave tile 64x64.
// Abuf: activations [128][264] fp16 (pad 264 to spread LDS banks).
// Wb: double-buffered W K-chunk [n=256][k=32] fp16 (B-frags contiguous).
__global__ __launch_bounds__(512) void kmain(const void* inpos, char* ws, void* outp, int Npts){
  __shared__ __align__(16) unsigned short Abuf[128 * 264];
  __shared__ __align__(16) unsigned short Wb[2 * 8192];
  __shared__ __align__(16) float cbuf[7680];   // sbs[1536] sbh[1536] A2pi[3072] g[1536]
  float* sbs_p = cbuf;
  float* sbh_p = cbuf + 1536;
  float* a2_p  = cbuf + 3072;
  float* g_p   = cbuf + 6144;

  const int tid = threadIdx.x;
  const int flag = *(const int*)ws;
  const size_t wt_off = 16 + (size_t)NLVL * Npts * 8;
  const unsigned short* wt = (const unsigned short*)(ws + wt_off);
  const float* cst = (const float*)(ws + wt_off + (size_t)12 * 65536 * 2);
  const float* gf = (const float*)(ws + 16);
  const int r0 = blockIdx.x * 128;

  const int sn = tid >> 1, skk = (tid & 1) * 16;
  uint4 pa, pb;
  { // prefetch chunk (wi=0, kc=0)
    const uint4* p = (const uint4*)(wt + sn * 256 + skk);
    pa = p[0]; pb = p[1];
  }
  for (int idx = tid; idx < 6144; idx += 512) cbuf[idx] = cst[1024 + idx];
  for (int idx = tid; idx < 1536; idx += 512){
    int l = idx >> 8, j = idx & 255;
    g_p[idx] = gf[(size_t)l * Npts * 2 + (size_t)r0 * 2 + j];
  }
  { // layer 0: x = sin(5*(pos@W0 + b0)) -> Abuf (fp16)
    int lr = tid >> 2, c0 = (tid & 3) * 64;
    long bb = (long)(r0 + lr) * 3;
    float p0v = ldx(inpos, bb + 0, flag), p1v = ldx(inpos, bb + 1, flag), p2v = ldx(inpos, bb + 2, flag);
    for (int j = 0; j < 64; j++){
      int d = c0 + j;
      float v = __sinf(p0v * cst[d] + p1v * cst[256 + d] + p2v * cst[512 + d] + cst[768 + d]);
      Abuf[lr * 264 + d] = f2h(v);
    }
  }
  { // commit prefetched chunk 0 into buffer 0
    uint4* dw = (uint4*)(Wb + sn * 32 + skk);
    dw[0] = pa; dw[1] = pb;
  }
  __syncthreads();

  const int lane = tid & 63, wv = tid >> 6;
  const int q = lane >> 4, sx = lane & 15;
  const int wrow = (wv >> 2) * 64, wcol = (wv & 3) * 64;
  int aoff[4], boff[4];
  #pragma unroll
  for (int rt = 0; rt < 4; rt++) aoff[rt] = (wrow + rt * 16 + sx) * 264 + q * 8;
  #pragma unroll
  for (int ct = 0; ct < 4; ct++) boff[ct] = (wcol + ct * 16 + sx) * 32 + q * 8;

  const f4v zf = {0.f, 0.f, 0.f, 0.f};
  f4v xo[4][4];
  #pragma unroll
  for (int a = 0; a < 4; a++)
    #pragma unroll
    for (int b = 0; b < 4; b++) xo[a][b] = zf;

  int cur = 0;
  #pragma unroll 1
  for (int s = 0; s < 12; s++){
    const int li = s >> 1;
    const int wi = (s & 1) ? (6 + li) : li;
    f4v acc[4][4];
    #pragma unroll
    for (int a = 0; a < 4; a++)
      #pragma unroll
      for (int b = 0; b < 4; b++) acc[a][b] = zf;
    #pragma unroll 1
    for (int kc = 0; kc < 8; kc++){
      const bool havenext = !(s == 11 && kc == 7);
      if (havenext){
        int nwi, nkc;
        if (kc < 7){ nwi = wi; nkc = kc + 1; }
        else { int s2 = s + 1; nwi = (s2 & 1) ? (6 + (s2 >> 1)) : (s2 >> 1); nkc = 0; }
        const uint4* p = (const uint4*)(wt + nwi * 65536 + sn * 256 + nkc * 32 + skk);
        pa = p[0]; pb = p[1];
      }
      h8v bfr[4], afr[4];
      const unsigned short* wc = Wb + cur * 8192;
      #pragma unroll
      for (int ct = 0; ct < 4; ct++) bfr[ct] = *(const h8v*)(wc + boff[ct]);
      #pragma unroll
      for (int rt = 0; rt < 4; rt++) afr[rt] = *(const h8v*)(Abuf + aoff[rt] + kc * 32);
      #pragma unroll
      for (int rt = 0; rt < 4; rt++)
        #pragma unroll
        for (int ct = 0; ct < 4; ct++)
          acc[rt][ct] = __builtin_amdgcn_mfma_f32_16x16x32_f16(afr[rt], bfr[ct], acc[rt][ct], 0, 0, 0);
      if (havenext){
        uint4* dw = (uint4*)(Wb + (cur ^ 1) * 8192 + sn * 32 + skk);
        dw[0] = pa; dw[1] = pb;
      }
      __syncthreads();
      cur ^= 1;
    }
    if ((s & 1) == 0){
      // epilogue 1: x = sin(5y + 5bs) + sin(2*pi*sigma*(A0*g0 + A1*g1)) -> Abuf
      #pragma unroll
      for (int ct = 0; ct < 4; ct++){
        int col = wcol + ct * 16 + sx;
        float sb = sbs_p[li * 256 + col];
        float a0 = a2_p[(li * 2 + 0) * 256 + col];
        float a1 = a2_p[(li * 2 + 1) * 256 + col];
        #pragma unroll
        for (int rt = 0; rt < 4; rt++)
          #pragma unroll
          for (int r = 0; r < 4; r++){
            int row = wrow + rt * 16 + q * 4 + r;
            float gg0 = g_p[li * 256 + row * 2], gg1 = g_p[li * 256 + row * 2 + 1];
            float v = __sinf(5.0f * acc[rt][ct][r] + sb) + __sinf(a0 * gg0 + a1 * gg1);
            Abuf[row * 264 + col] = f2h(v);
          }
      }
      __syncthreads();
    } else {
      // epilogue 2: x_out += sin(10z + 10bh)
      #pragma unroll
      for (int ct = 0; ct < 4; ct++){
        int col = wcol + ct * 16 + sx;
        float sb = sbh_p[li * 256 + col];
        #pragma unroll
        for (int rt = 0; rt < 4; rt++)
          #pragma unroll
          for (int r = 0; r < 4; r++)
            xo[rt][ct][r] += __sinf(10.0f * acc[rt][ct][r] + sb);
      }
    }
  }
  if (flag){
    unsigned short* ob = (unsigned short*)outp;
    #pragma unroll
    for (int rt = 0; rt < 4; rt++)
      #pragma unroll
      for (int ct = 0; ct < 4; ct++)
        #pragma unroll
        for (int r = 0; r < 4; r++){
          long row = (long)r0 + wrow + rt * 16 + q * 4 + r;
          ob[row * 256 + (wcol + ct * 16 + sx)] = f2b(xo[rt][ct][r]);
        }
  } else {
    float* of = (float*)outp;
    #pragma unroll
    for (int rt = 0; rt < 4; rt++)
      #pragma unroll
      for (int ct = 0; ct < 4; ct++)
        #pragma unroll
        for (int r = 0; r < 4; r++){
          long row = (long)r0 + wrow + rt * 16 + q * 4 + r;
          of[row * 256 + (wcol + ct * 16 + sx)] = xo[rt][ct][r];
        }
  }
}

extern "C" void kernel_launch(void* const* d_in, const int* in_sizes, int n_in,
                              void* d_out, int out_size, void* d_ws, size_t ws_size,
                              hipStream_t stream){
  (void)n_in; (void)out_size; (void)ws_size;
  const void* inpos = d_in[0];
  const void* tbl   = d_in[1];
  const void* ffnA  = d_in[2];
  const void* W0    = d_in[3];
  const void* b0    = d_in[4];
  const void* Wsv   = d_in[5];
  const void* bsv   = d_in[6];
  const void* Whv   = d_in[7];
  const void* bhv   = d_in[8];
  int Npts = in_sizes[0] / 3;              // 262144
  char* ws = (char*)d_ws;
  kdetect<<<1, 128, 0, stream>>>((const unsigned short*)inpos, (int*)d_ws);
  kconsts<<<28, 256, 0, stream>>>(ffnA, W0, b0, bsv, bhv, ws, Npts);
  kwt<<<3072, 256, 0, stream>>>(Wsv, Whv, ws, Npts);
  kgrid<<<dim3(Npts / 256, NLVL), 256, 0, stream>>>(inpos, tbl, ws, Npts);
  kmain<<<Npts / 128, 512, 0, stream>>>(inpos, ws, d_out, Npts);
}